// Round 1
// baseline (76.130 us; speedup 1.0000x reference)
//
#include <hip/hip_runtime.h>
#include <cstdint>
#include <cstddef>

// HierarchicalDenseLayer: base = ctx @ Wcat (bf16 MFMA), then per-row kinematic
// chain of 3x3 linears + tanh*pi, fused in one kernel.

#define CTXD 512
#define NCOL 66          // 22 joints * 3
#define KT   16          // 512 / 32 k-steps
#define NT   5           // ceil(66/16) N-tiles (padded to 80)
#define ROWS_PER_BLOCK 128
#define LDS_STRIDE 67    // 66 + 1 pad -> stride%32==3, conflict-free column reads

typedef __attribute__((ext_vector_type(8))) short  short8;  // 8 bf16 (4 VGPRs)
typedef __attribute__((ext_vector_type(4))) float  f32x4;   // MFMA accum

__device__ __forceinline__ unsigned short f2bf(float x) {
  // round-to-nearest-even fp32 -> bf16 bit pattern
  unsigned u = __float_as_uint(x);
  unsigned r = (u + 0x7FFFu + ((u >> 16) & 1u)) >> 16;
  return (unsigned short)r;
}

__device__ __forceinline__ float tanhpi(float x) {
  // pi * tanh(x) = pi * (1 - 2/(e^{2x}+1)); safe at +/-inf (no NaN)
  float t = exp2f(x * 2.885390081777927f);            // e^{2x}
  return 3.1415926f - 6.2831852f * __builtin_amdgcn_rcpf(t + 1.0f);
}

// ---------------------------------------------------------------------------
// Prep: pack Wcat (512 x 66, bf16, zero-padded to 80 cols) into MFMA B-frag
// order: wf[((kt*NT + nt)*64 + lane)*8 + j] = Wcat[kt*32 + (lane>>4)*8 + j]
//                                                 [nt*16 + (lane&15)]
// ---------------------------------------------------------------------------
__global__ void prep_wfrag(const float* __restrict__ W0,
                           const float* __restrict__ W,
                           unsigned short* __restrict__ wf) {
  int idx = blockIdx.x * blockDim.x + threadIdx.x;
  if (idx >= KT * NT * 64 * 8) return;
  int j    = idx & 7;
  int lane = (idx >> 3) & 63;
  int rest = idx >> 9;
  int nt   = rest % NT;
  int kt   = rest / NT;
  int k    = kt * 32 + (lane >> 4) * 8 + j;
  int col  = nt * 16 + (lane & 15);
  float v = 0.f;
  if (col < 3)          v = W0[k * 3 + col];
  else if (col < NCOL)  v = W[(col / 3) * (515 * 3) + k * 3 + (col % 3)];
  wf[idx] = f2bf(v);
}

// ---------------------------------------------------------------------------
// Main: GEMM (4 waves x 2 M-tiles x 5 N-tiles) + per-row chain epilogue
// ---------------------------------------------------------------------------
__global__ __launch_bounds__(256) void hdl_main(
    const float* __restrict__ ctx,   // [B, 512]
    const float* __restrict__ b0,    // [3]
    const float* __restrict__ W,     // [22, 515, 3]
    const float* __restrict__ bflat, // [22, 3] flat = bcat[3..65] (0..2 unused)
    const unsigned short* __restrict__ wf,  // packed B frags
    float* __restrict__ out)         // [B, 66]
{
  __shared__ float lds[ROWS_PER_BLOCK * LDS_STRIDE];

  const int tid  = threadIdx.x;
  const int lane = tid & 63;
  const int wave = tid >> 6;
  const int r16  = lane & 15;   // M-row within tile / N-col within tile
  const int kg   = lane >> 4;   // k-group 0..3
  const long blockRow = (long)blockIdx.x * ROWS_PER_BLOCK;

  f32x4 acc[2][NT] = {};

  // per-lane bias for its 5 output columns
  float bias[NT];
#pragma unroll
  for (int n = 0; n < NT; ++n) {
    int col = n * 16 + r16;
    bias[n] = (col < 3) ? b0[col] : ((col < NCOL) ? bflat[col] : 0.f);
  }

  const float* a0 = ctx + (blockRow + wave * 32 + r16) * CTXD + kg * 8;

  for (int kt = 0; kt < KT; ++kt) {
    short8 bfr[NT];
#pragma unroll
    for (int n = 0; n < NT; ++n)
      bfr[n] = *(const short8*)(wf + (size_t)((kt * NT + n) * 64 + lane) * 8);

#pragma unroll
    for (int m = 0; m < 2; ++m) {
      const float* ap = a0 + (size_t)m * 16 * CTXD + kt * 32;
      float4 f0 = *(const float4*)(ap);
      float4 f1 = *(const float4*)(ap + 4);
      short8 afr;
      afr[0] = (short)f2bf(f0.x); afr[1] = (short)f2bf(f0.y);
      afr[2] = (short)f2bf(f0.z); afr[3] = (short)f2bf(f0.w);
      afr[4] = (short)f2bf(f1.x); afr[5] = (short)f2bf(f1.y);
      afr[6] = (short)f2bf(f1.z); afr[7] = (short)f2bf(f1.w);
#pragma unroll
      for (int n = 0; n < NT; ++n)
        acc[m][n] = __builtin_amdgcn_mfma_f32_16x16x32_bf16(
            afr, bfr[n], acc[m][n], 0, 0, 0);
    }
  }

  // accum -> LDS as [row][col] with +bias
  // D layout: col = lane&15, row = (lane>>4)*4 + reg   [measured m89/m91]
#pragma unroll
  for (int m = 0; m < 2; ++m) {
#pragma unroll
    for (int n = 0; n < NT; ++n) {
      int col = n * 16 + r16;
      if (col < NCOL) {
        int rb = wave * 32 + m * 16 + kg * 4;
#pragma unroll
        for (int q = 0; q < 4; ++q)
          lds[(rb + q) * LDS_STRIDE + col] = acc[m][n][q] + bias[n];
      }
    }
  }
  __syncthreads();

  // per-row kinematic chain (1 thread per row; threads 128..255 idle here)
  if (tid < ROWS_PER_BLOCK) {
    float* row = lds + tid * LDS_STRIDE;
    float J[22][3];
#pragma unroll
    for (int c = 0; c < 3; ++c) J[0][c] = tanhpi(row[c]);

    constexpr int EP[21] = {0,2,5,8, 0,1,4,7, 0,3,6,9,12, 9,14,17,19, 9,13,16,18};
    constexpr int EC[21] = {2,5,8,11, 1,4,7,10, 3,6,9,12,15, 14,17,19,21, 13,16,18,20};
#pragma unroll
    for (int e = 0; e < 21; ++e) {
      const int p  = EP[e];
      const int ch = EC[e];
      const float* wp = W + ch * 1545 + 1536;   // W[ch][512.. ,:], uniform -> s_load
#pragma unroll
      for (int c = 0; c < 3; ++c) {
        float s = row[3 * ch + c];
        s += J[p][0] * wp[c] + J[p][1] * wp[3 + c] + J[p][2] * wp[6 + c];
        J[ch][c] = tanhpi(s);
      }
    }
    // write joint values back over the base slots
#pragma unroll
    for (int jj = 0; jj < 22; ++jj)
#pragma unroll
      for (int c = 0; c < 3; ++c) row[3 * jj + c] = J[jj][c];
  }
  __syncthreads();

  // coalesced copy: block's output region is contiguous [blockRow*66, +128*66)
  const size_t outBase = (size_t)blockRow * NCOL;
  for (int i = tid; i < ROWS_PER_BLOCK * NCOL; i += 256) {
    int r = i / NCOL;
    int c = i - r * NCOL;
    out[outBase + i] = lds[r * LDS_STRIDE + c];
  }
}

extern "C" void kernel_launch(void* const* d_in, const int* in_sizes, int n_in,
                              void* d_out, int out_size, void* d_ws, size_t ws_size,
                              hipStream_t stream) {
  const float* ctx  = (const float*)d_in[0];
  const float* W0   = (const float*)d_in[1];
  const float* b0   = (const float*)d_in[2];
  const float* W    = (const float*)d_in[3];
  const float* bfl  = (const float*)d_in[4];
  unsigned short* wf = (unsigned short*)d_ws;   // 80 KB packed weights

  int prep_elems = KT * NT * 64 * 8;            // 40960
  hipLaunchKernelGGL(prep_wfrag, dim3((prep_elems + 255) / 256), dim3(256), 0,
                     stream, W0, W, wf);

  int nrows = out_size / NCOL;                  // 131072
  hipLaunchKernelGGL(hdl_main, dim3(nrows / ROWS_PER_BLOCK), dim3(256), 0,
                     stream, ctx, b0, W, bfl, wf, (float*)d_out);
}

// Round 2
// 64.039 us; speedup vs baseline: 1.1888x; 1.1888x over previous
//
#include <hip/hip_runtime.h>
#include <cstdint>
#include <cstddef>

// HierarchicalDenseLayer: base = ctx @ Wcat (bf16 MFMA, A staged via
// global_load_lds for contiguous HBM segments), then per-row kinematic chain.

#define CTXD 512
#define NCOL 66          // 22 joints * 3
#define KT   16          // 512 / 32 k-steps
#define NT   5           // ceil(66/16) N-tiles (padded to 80)
#define NCH  8           // K-chunks; each = 2 k-steps = 64 cols = 256 B/row
#define RPB  128         // rows per block (4 waves x 32 rows)
#define LDS_STRIDE 67    // out tile stride: 66+1, conflict-free column reads

typedef __attribute__((ext_vector_type(8))) short  short8;  // 8 bf16
typedef __attribute__((ext_vector_type(4))) float  f32x4;   // MFMA accum

__device__ __forceinline__ unsigned short f2bf(float x) {
  unsigned u = __float_as_uint(x);
  return (unsigned short)((u + 0x7FFFu + ((u >> 16) & 1u)) >> 16);
}

__device__ __forceinline__ unsigned cvt2(float a, float b) {
  // dst[15:0]=bf16(a), dst[31:16]=bf16(b)
  unsigned r;
  asm("v_cvt_pk_bf16_f32 %0, %1, %2" : "=v"(r) : "v"(a), "v"(b));
  return r;
}

__device__ __forceinline__ float tanhpi(float x) {
  // pi * tanh(x) = pi * (1 - 2/(e^{2x}+1)); safe at +/-inf
  float t = exp2f(x * 2.885390081777927f);
  return 3.1415926f - 6.2831852f * __builtin_amdgcn_rcpf(t + 1.0f);
}

// ---------------------------------------------------------------------------
// Prep: pack Wcat (512 x 66 -> pad 80) into MFMA B-frag order:
// wf[((kt*NT + nt)*64 + lane)*8 + j] = Wcat[kt*32 + (lane>>4)*8 + j][nt*16 + (lane&15)]
// ---------------------------------------------------------------------------
__global__ void prep_wfrag(const float* __restrict__ W0,
                           const float* __restrict__ W,
                           unsigned short* __restrict__ wf) {
  int idx = blockIdx.x * blockDim.x + threadIdx.x;
  if (idx >= KT * NT * 64 * 8) return;
  int j    = idx & 7;
  int lane = (idx >> 3) & 63;
  int rest = idx >> 9;
  int nt   = rest % NT;
  int kt   = rest / NT;
  int k    = kt * 32 + (lane >> 4) * 8 + j;
  int col  = nt * 16 + (lane & 15);
  float v = 0.f;
  if (col < 3)          v = W0[k * 3 + col];
  else if (col < NCOL)  v = W[(col / 3) * (515 * 3) + k * 3 + (col % 3)];
  wf[idx] = f2bf(v);
}

// ---------------------------------------------------------------------------
// Main kernel
// ---------------------------------------------------------------------------
__global__ __launch_bounds__(256, 4) void hdl_main(
    const float* __restrict__ ctx,   // [B, 512]
    const float* __restrict__ b0,    // [3]
    const float* __restrict__ W,     // [22, 515, 3]
    const float* __restrict__ bflat, // [22*3]
    const unsigned short* __restrict__ wf,
    float* __restrict__ out)         // [B, 66]
{
  // union: [0, 8192) floats = 4 waves x (32 rows x 64 floats) staging;
  // whole array = 128 x 67 output tile for the epilogue.
  __shared__ float smem[RPB * LDS_STRIDE];   // 8576 floats = 34.3 KB

  const int tid  = threadIdx.x;
  const int lane = tid & 63;
  const int wave = tid >> 6;
  const int r16  = lane & 15;
  const int kg   = lane >> 4;
  const long blockRow = (long)blockIdx.x * RPB;

  f32x4 acc[2][NT] = {};

  float bias[NT];
#pragma unroll
  for (int n = 0; n < NT; ++n) {
    int col = n * 16 + r16;
    bias[n] = (col < 3) ? b0[col] : ((col < NCOL) ? bflat[col] : 0.f);
  }

  // wave-private staging: 32 rows x 64 floats (256 B/row), linear row-major
  float* stage = smem + wave * 2048;
  // gll instruction j covers rows (wave*32 + j*4 .. +3), 256 B each:
  // lane L -> row +(L>>4), bytes (L&15)*16 within the chunk's 256 B
  const float* srcBase =
      ctx + (blockRow + wave * 32 + (lane >> 4)) * (long)CTXD + (lane & 15) * 4;

  for (int c = 0; c < NCH; ++c) {
#pragma unroll
    for (int j = 0; j < 8; ++j) {
      const float* s = srcBase + (size_t)j * 4 * CTXD + c * 64;
      __builtin_amdgcn_global_load_lds(
          (const __attribute__((address_space(1))) void*)s,
          (__attribute__((address_space(3))) void*)(stage + j * 256),
          16, 0, 0);
    }
    asm volatile("s_waitcnt vmcnt(0)" ::: "memory");

#pragma unroll
    for (int t = 0; t < 2; ++t) {           // k-steps within chunk
      const int kt = c * 2 + t;
      short8 bfr[NT];
#pragma unroll
      for (int n = 0; n < NT; ++n)
        bfr[n] = *(const short8*)(wf + (size_t)((kt * NT + n) * 64 + lane) * 8);

#pragma unroll
      for (int m = 0; m < 2; ++m) {
        const float* fp = stage + (m * 16 + r16) * 64 + t * 32 + kg * 8;
        float4 f0 = *(const float4*)(fp);
        float4 f1 = *(const float4*)(fp + 4);
        union { short8 s; unsigned u[4]; } A;
        A.u[0] = cvt2(f0.x, f0.y);
        A.u[1] = cvt2(f0.z, f0.w);
        A.u[2] = cvt2(f1.x, f1.y);
        A.u[3] = cvt2(f1.z, f1.w);
#pragma unroll
        for (int n = 0; n < NT; ++n)
          acc[m][n] = __builtin_amdgcn_mfma_f32_16x16x32_bf16(
              A.s, bfr[n], acc[m][n], 0, 0, 0);
      }
    }
    asm volatile("" ::: "memory");
  }

  // staging region is about to be overwritten by the output tile
  __syncthreads();

  // accum -> LDS [row][col] with +bias.  D layout: col=lane&15, row=(lane>>4)*4+reg
#pragma unroll
  for (int m = 0; m < 2; ++m) {
#pragma unroll
    for (int n = 0; n < NT; ++n) {
      int col = n * 16 + r16;
      if (col < NCOL) {
        int rb = wave * 32 + m * 16 + kg * 4;
#pragma unroll
        for (int q = 0; q < 4; ++q)
          smem[(rb + q) * LDS_STRIDE + col] = acc[m][n][q] + bias[n];
      }
    }
  }
  __syncthreads();

  // per-row kinematic chain (1 thread per row)
  if (tid < RPB) {
    float* row = smem + tid * LDS_STRIDE;
    float J[22][3];
#pragma unroll
    for (int cc = 0; cc < 3; ++cc) J[0][cc] = tanhpi(row[cc]);

    constexpr int EP[21] = {0,2,5,8, 0,1,4,7, 0,3,6,9,12, 9,14,17,19, 9,13,16,18};
    constexpr int EC[21] = {2,5,8,11, 1,4,7,10, 3,6,9,12,15, 14,17,19,21, 13,16,18,20};
#pragma unroll
    for (int e = 0; e < 21; ++e) {
      const int p  = EP[e];
      const int ch = EC[e];
      const float* wp = W + ch * 1545 + 1536;   // W[ch][512:515][:], wave-uniform
#pragma unroll
      for (int cc = 0; cc < 3; ++cc) {
        float s = row[3 * ch + cc];
        s += J[p][0] * wp[cc] + J[p][1] * wp[3 + cc] + J[p][2] * wp[6 + cc];
        J[ch][cc] = tanhpi(s);
      }
    }
#pragma unroll
    for (int jj = 0; jj < 22; ++jj)
#pragma unroll
      for (int cc = 0; cc < 3; ++cc) row[3 * jj + cc] = J[jj][cc];
  }
  __syncthreads();

  // coalesced contiguous store of the block's [128 x 66] output
  const size_t outBase = (size_t)blockRow * NCOL;
  for (int i = tid; i < RPB * NCOL; i += 256) {
    int r = i / NCOL;
    int cc = i - r * NCOL;
    out[outBase + i] = smem[r * LDS_STRIDE + cc];
  }
}

extern "C" void kernel_launch(void* const* d_in, const int* in_sizes, int n_in,
                              void* d_out, int out_size, void* d_ws, size_t ws_size,
                              hipStream_t stream) {
  const float* ctx  = (const float*)d_in[0];
  const float* W0   = (const float*)d_in[1];
  const float* b0   = (const float*)d_in[2];
  const float* W    = (const float*)d_in[3];
  const float* bfl  = (const float*)d_in[4];
  unsigned short* wf = (unsigned short*)d_ws;   // 80 KB packed weights

  int prep_elems = KT * NT * 64 * 8;            // 40960
  hipLaunchKernelGGL(prep_wfrag, dim3((prep_elems + 255) / 256), dim3(256), 0,
                     stream, W0, W, wf);

  int nrows = out_size / NCOL;                  // 131072
  hipLaunchKernelGGL(hdl_main, dim3(nrows / RPB), dim3(256), 0,
                     stream, ctx, b0, W, bfl, wf, (float*)d_out);
}

// Round 3
// 63.730 us; speedup vs baseline: 1.1946x; 1.0048x over previous
//
#include <hip/hip_runtime.h>
#include <cstdint>
#include <cstddef>

// HierarchicalDenseLayer: base = ctx @ Wcat (bf16 MFMA), A staged via
// double-buffered global_load_lds with counted vmcnt (T3/T4) and XOR-swizzled
// layout (T2, pre-swizzled global source per rule 21); then per-row chain.

#define CTXD 512
#define NCOL 66          // 22 joints * 3
#define KT   16          // 512 / 32 k-steps
#define NT   5           // ceil(66/16) N-tiles (padded to 80)
#define RPB  128         // rows per block (4 waves x 32 rows)
#define LDS_STRIDE 67    // out tile stride: 66+1, conflict-free column reads

typedef __attribute__((ext_vector_type(8))) short  short8;  // 8 bf16
typedef __attribute__((ext_vector_type(4))) float  f32x4;   // MFMA accum

__device__ __forceinline__ unsigned short f2bf(float x) {
  unsigned u = __float_as_uint(x);
  return (unsigned short)((u + 0x7FFFu + ((u >> 16) & 1u)) >> 16);
}

__device__ __forceinline__ unsigned cvt2(float a, float b) {
  unsigned r;
  asm("v_cvt_pk_bf16_f32 %0, %1, %2" : "=v"(r) : "v"(a), "v"(b));
  return r;
}

__device__ __forceinline__ float tanhpi(float x) {
  // pi * tanh(x) = pi * (1 - 2/(e^{2x}+1)); safe at +/-inf
  float t = exp2f(x * 2.885390081777927f);
  return 3.1415926f - 6.2831852f * __builtin_amdgcn_rcpf(t + 1.0f);
}

// ---------------------------------------------------------------------------
// Prep: pack Wcat (512 x 66 -> pad 80) into MFMA B-frag order:
// wf[((kt*NT+nt)*64+lane)*8+j] = Wcat[kt*32 + (lane>>4)*8 + j][nt*16 + (lane&15)]
// ---------------------------------------------------------------------------
__global__ void prep_wfrag(const float* __restrict__ W0,
                           const float* __restrict__ W,
                           unsigned short* __restrict__ wf) {
  int idx = blockIdx.x * blockDim.x + threadIdx.x;
  if (idx >= KT * NT * 64 * 8) return;
  int j    = idx & 7;
  int lane = (idx >> 3) & 63;
  int rest = idx >> 9;
  int nt   = rest % NT;
  int kt   = rest / NT;
  int k    = kt * 32 + (lane >> 4) * 8 + j;
  int col  = nt * 16 + (lane & 15);
  float v = 0.f;
  if (col < 3)          v = W0[k * 3 + col];
  else if (col < NCOL)  v = W[(col / 3) * (515 * 3) + k * 3 + (col % 3)];
  wf[idx] = f2bf(v);
}

// ---------------------------------------------------------------------------
// Main kernel
// ---------------------------------------------------------------------------
__global__ __launch_bounds__(256, 4) void hdl_main(
    const float* __restrict__ ctx,   // [B, 512]
    const float* __restrict__ b0,    // [3]
    const float* __restrict__ W,     // [22, 515, 3]
    const float* __restrict__ bflat, // [22*3]
    const unsigned short* __restrict__ wf,
    float* __restrict__ out)         // [B, 66]
{
  // union: [0, 8192) floats = 4 waves x 2 k-step buffers x 1024 floats;
  // whole array = 128 x 67 output tile for the epilogue.
  __shared__ float smem[RPB * LDS_STRIDE];   // 8576 floats = 34.3 KB

  const int tid  = threadIdx.x;
  const int lane = tid & 63;
  const int wave = tid >> 6;
  const int r16  = lane & 15;
  const int kg   = lane >> 4;
  const long blockRow = (long)blockIdx.x * RPB;

  f32x4 acc[2][NT] = {};

  float bias[NT];
#pragma unroll
  for (int n = 0; n < NT; ++n) {
    int col = n * 16 + r16;
    bias[n] = (col < 3) ? b0[col] : ((col < NCOL) ? bflat[col] : 0.f);
  }

  // wave-private staging: 2 buffers x (32 rows x 32 floats), linear per gll.
  // Swizzle: LDS 16B-unit u of row r holds global unit u ^ (r&7); achieved by
  // pre-swizzling the per-lane global source (dest stays linear, rule 21).
  float* stage = smem + wave * 2048;
  // gll inst j covers rows j*8+(lane>>3); lane's 16B dest unit = lane&7
  const float* srcBase =
      ctx + (blockRow + wave * 32 + (lane >> 3)) * (long)CTXD
          + (((lane & 7) ^ (lane >> 3)) << 2);

#define ISSUE_GLL(ktv, buf)                                                    \
  {                                                                            \
    _Pragma("unroll")                                                          \
    for (int j = 0; j < 4; ++j) {                                              \
      const float* s = srcBase + (size_t)(j * 8) * CTXD + (ktv) * 32;          \
      __builtin_amdgcn_global_load_lds(                                        \
          (const __attribute__((address_space(1))) void*)s,                    \
          (__attribute__((address_space(3))) void*)((buf) + j * 256),          \
          16, 0, 0);                                                           \
    }                                                                          \
  }

  ISSUE_GLL(0, stage)                         // prologue: kt=0 in flight (4 ops)

#pragma unroll
  for (int kt = 0; kt < KT; ++kt) {
    const float* cur = stage + (kt & 1) * 1024;
    float* nxt = stage + ((kt + 1) & 1) * 1024;

    // b-frags for kt: issued BEFORE next gll batch so vmcnt(4) covers them
    short8 bfr[NT];
#pragma unroll
    for (int n = 0; n < NT; ++n)
      bfr[n] = *(const short8*)(wf + (size_t)((kt * NT + n) * 64 + lane) * 8);

    if (kt < KT - 1) {
      ISSUE_GLL(kt + 1, nxt)
      // outstanding: gll(kt) x4 (oldest), bfr(kt) x5, gll(kt+1) x4 (newest)
      asm volatile("s_waitcnt vmcnt(4)" ::: "memory");
    } else {
      asm volatile("s_waitcnt vmcnt(0)" ::: "memory");
    }

#pragma unroll
    for (int m = 0; m < 2; ++m) {
      const int row = m * 16 + r16;
      const float* rbase = cur + row * 32;
      const int rx = r16 & 7;
      float4 f0 = *(const float4*)(rbase + ((((kg * 2)     ) ^ rx) << 2));
      float4 f1 = *(const float4*)(rbase + ((((kg * 2) + 1 ) ^ rx) << 2));
      union { short8 s; unsigned u[4]; } A;
      A.u[0] = cvt2(f0.x, f0.y);
      A.u[1] = cvt2(f0.z, f0.w);
      A.u[2] = cvt2(f1.x, f1.y);
      A.u[3] = cvt2(f1.z, f1.w);
#pragma unroll
      for (int n = 0; n < NT; ++n)
        acc[m][n] = __builtin_amdgcn_mfma_f32_16x16x32_bf16(
            A.s, bfr[n], acc[m][n], 0, 0, 0);
    }
  }

  // staging region is about to be overwritten by the output tile
  __syncthreads();

  // accum -> LDS [row][col] with +bias.  D layout: col=lane&15, row=(lane>>4)*4+reg
#pragma unroll
  for (int m = 0; m < 2; ++m) {
#pragma unroll
    for (int n = 0; n < NT; ++n) {
      int col = n * 16 + r16;
      if (col < NCOL) {
        int rb = wave * 32 + m * 16 + kg * 4;
#pragma unroll
        for (int q = 0; q < 4; ++q)
          smem[(rb + q) * LDS_STRIDE + col] = acc[m][n][q] + bias[n];
      }
    }
  }
  __syncthreads();

  // per-row kinematic chain (1 thread per row)
  if (tid < RPB) {
    float* row = smem + tid * LDS_STRIDE;
    float J[22][3];
#pragma unroll
    for (int cc = 0; cc < 3; ++cc) J[0][cc] = tanhpi(row[cc]);

    constexpr int EP[21] = {0,2,5,8, 0,1,4,7, 0,3,6,9,12, 9,14,17,19, 9,13,16,18};
    constexpr int EC[21] = {2,5,8,11, 1,4,7,10, 3,6,9,12,15, 14,17,19,21, 13,16,18,20};
#pragma unroll
    for (int e = 0; e < 21; ++e) {
      const int p  = EP[e];
      const int ch = EC[e];
      const float* wp = W + ch * 1545 + 1536;   // W[ch][512:515][:], wave-uniform
#pragma unroll
      for (int cc = 0; cc < 3; ++cc) {
        float s = row[3 * ch + cc];
        s += J[p][0] * wp[cc] + J[p][1] * wp[3 + cc] + J[p][2] * wp[6 + cc];
        J[ch][cc] = tanhpi(s);
      }
    }
#pragma unroll
    for (int jj = 0; jj < 22; ++jj)
#pragma unroll
      for (int cc = 0; cc < 3; ++cc) row[3 * jj + cc] = J[jj][cc];
  }
  __syncthreads();

  // coalesced contiguous store of the block's [128 x 66] output
  const size_t outBase = (size_t)blockRow * NCOL;
  for (int i = tid; i < RPB * NCOL; i += 256) {
    int r = i / NCOL;
    int cc = i - r * NCOL;
    out[outBase + i] = smem[r * LDS_STRIDE + cc];
  }
}

extern "C" void kernel_launch(void* const* d_in, const int* in_sizes, int n_in,
                              void* d_out, int out_size, void* d_ws, size_t ws_size,
                              hipStream_t stream) {
  const float* ctx  = (const float*)d_in[0];
  const float* W0   = (const float*)d_in[1];
  const float* b0   = (const float*)d_in[2];
  const float* W    = (const float*)d_in[3];
  const float* bfl  = (const float*)d_in[4];
  unsigned short* wf = (unsigned short*)d_ws;   // 80 KB packed weights

  int prep_elems = KT * NT * 64 * 8;            // 40960
  hipLaunchKernelGGL(prep_wfrag, dim3((prep_elems + 255) / 256), dim3(256), 0,
                     stream, W0, W, wf);

  int nrows = out_size / NCOL;                  // 131072
  hipLaunchKernelGGL(hdl_main, dim3(nrows / RPB), dim3(256), 0,
                     stream, ctx, b0, W, bfl, wf, (float*)d_out);
}